// Round 7
// baseline (1275.440 us; speedup 1.0000x reference)
//
#include <hip/hip_runtime.h>
#include <hip/hip_bf16.h>

#define Bn 64
#define Tn 512
#define En 128
#define Hn 64
#define Gn 256   // 4*H
#define Cn 20

typedef float f32x2 __attribute__((ext_vector_type(2)));

__device__ __forceinline__ float sigf(float x)      { return 1.f/(1.f+__expf(-x)); }
__device__ __forceinline__ float tanhfast(float x)  { return 2.f/(1.f+__expf(-2.f*x)) - 1.f; }

// ---------------------------------------------------------------------------
// Kernel A: Z0[b*T+t][j] = (word_emb[ids[b,t]] + pos_emb[t]) @ Wx_b0 + b_b0
// ---------------------------------------------------------------------------
__global__ __launch_bounds__(256, 1) void emb_proj_kernel(
    const int* __restrict__ x, const float* __restrict__ word_emb,
    const float* __restrict__ pos_emb, const float* __restrict__ wx,
    const float* __restrict__ bias, float* __restrict__ z0)
{
  __shared__ float emb[64][En];     // 32 KB
  __shared__ float wxl[32][Gn];     // 32 KB
  const int tid  = threadIdx.x;
  const int row0 = blockIdx.x * 64;

  #pragma unroll
  for (int it = 0; it < 8; ++it) {
    int idx = it*256 + tid;
    int rr  = idx >> 5;
    int e4  = (idx & 31) << 2;
    int r   = row0 + rr;
    int b   = r >> 9;
    int t   = r & (Tn-1);
    int id  = x[b*3*Tn + t];
    float4 we = *reinterpret_cast<const float4*>(&word_emb[(size_t)id*En + e4]);
    float4 pe = *reinterpret_cast<const float4*>(&pos_emb[(size_t)t*En + e4]);
    *reinterpret_cast<float4*>(&emb[rr][e4]) =
        make_float4(we.x+pe.x, we.y+pe.y, we.z+pe.z, we.w+pe.w);
  }

  const int jc = tid & 63;
  const int rg = tid >> 6;
  float acc[16][4];
  float4 bb = *reinterpret_cast<const float4*>(&bias[jc*4]);
  #pragma unroll
  for (int r = 0; r < 16; ++r) { acc[r][0]=bb.x; acc[r][1]=bb.y; acc[r][2]=bb.z; acc[r][3]=bb.w; }

  for (int ec = 0; ec < 4; ++ec) {
    __syncthreads();
    #pragma unroll
    for (int it = 0; it < 8; ++it) {
      int idx = it*256 + tid;
      int ee  = idx >> 6;
      int j4  = (idx & 63) << 2;
      *reinterpret_cast<float4*>(&wxl[ee][j4]) =
          *reinterpret_cast<const float4*>(&wx[(size_t)(ec*32+ee)*Gn + j4]);
    }
    __syncthreads();
    for (int ee = 0; ee < 32; ++ee) {
      float4 w = *reinterpret_cast<const float4*>(&wxl[ee][jc*4]);
      #pragma unroll
      for (int r = 0; r < 16; ++r) {
        float xv = emb[rg*16+r][ec*32+ee];
        acc[r][0] = fmaf(xv, w.x, acc[r][0]);
        acc[r][1] = fmaf(xv, w.y, acc[r][1]);
        acc[r][2] = fmaf(xv, w.z, acc[r][2]);
        acc[r][3] = fmaf(xv, w.w, acc[r][3]);
      }
    }
  }
  #pragma unroll
  for (int r = 0; r < 16; ++r) {
    size_t row = (size_t)row0 + rg*16 + r;
    *reinterpret_cast<float4*>(&z0[row*Gn + jc*4]) =
        make_float4(acc[r][0], acc[r][1], acc[r][2], acc[r][3]);
  }
}

// ---------------------------------------------------------------------------
// Kernel A2: ZX1[b*T+t][j] = hb0[b,t,:] @ Wx_b1 + b_b1
// ---------------------------------------------------------------------------
__global__ __launch_bounds__(256, 1) void zx1_gemm_kernel(
    const float* __restrict__ hb0, const float* __restrict__ wx,
    const float* __restrict__ bias, float* __restrict__ zx1)
{
  __shared__ float xl[64][Hn];
  __shared__ float wl[32][Gn];
  const int tid  = threadIdx.x;
  const int row0 = blockIdx.x * 64;

  #pragma unroll
  for (int it = 0; it < 4; ++it) {
    int idx = it*256 + tid;
    int rr  = idx >> 4;
    int e4  = (idx & 15) << 2;
    *reinterpret_cast<float4*>(&xl[rr][e4]) =
        *reinterpret_cast<const float4*>(&hb0[((size_t)row0+rr)*Hn + e4]);
  }

  const int jc = tid & 63;
  const int rg = tid >> 6;
  float acc[16][4];
  float4 bb = *reinterpret_cast<const float4*>(&bias[jc*4]);
  #pragma unroll
  for (int r = 0; r < 16; ++r) { acc[r][0]=bb.x; acc[r][1]=bb.y; acc[r][2]=bb.z; acc[r][3]=bb.w; }

  for (int kc = 0; kc < 2; ++kc) {
    __syncthreads();
    #pragma unroll
    for (int it = 0; it < 8; ++it) {
      int idx = it*256 + tid;
      int kk  = idx >> 6;
      int j4  = (idx & 63) << 2;
      *reinterpret_cast<float4*>(&wl[kk][j4]) =
          *reinterpret_cast<const float4*>(&wx[(size_t)(kc*32+kk)*Gn + j4]);
    }
    __syncthreads();
    for (int kk = 0; kk < 32; ++kk) {
      float4 w = *reinterpret_cast<const float4*>(&wl[kk][jc*4]);
      #pragma unroll
      for (int r = 0; r < 16; ++r) {
        float xv = xl[rg*16+r][kc*32+kk];
        acc[r][0] = fmaf(xv, w.x, acc[r][0]);
        acc[r][1] = fmaf(xv, w.y, acc[r][1]);
        acc[r][2] = fmaf(xv, w.z, acc[r][2]);
        acc[r][3] = fmaf(xv, w.w, acc[r][3]);
      }
    }
  }
  #pragma unroll
  for (int r = 0; r < 16; ++r) {
    size_t row = (size_t)row0 + rg*16 + r;
    *reinterpret_cast<float4*>(&zx1[row*Gn + jc*4]) =
        make_float4(acc[r][0], acc[r][1], acc[r][2], acc[r][3]);
  }
}

// ---------------------------------------------------------------------------
// Recurrence: ONE wave per batch element. Lane l owns h-lane l and computes
// its OWN 4 gate columns {l, 64+l, 128+l, 192+l} via 128 v_pk_fma_f32
// (256 weight floats in f32x2 regs). No barriers, no z exchange; h broadcast
// via one wave-internal LDS write + 16 b128 reads (in-order DS pipe).
// z loads: 1 addr + 3 imm offsets, depth-2 pipeline, counted vmcnt.
// ---------------------------------------------------------------------------
#define PK_FMA(acc, hp, wp) \
  asm("v_pk_fma_f32 %0, %1, %2, %0" : "+v"(acc) : "v"(hp), "v"(wp))

template<bool IS_B0>
__global__ __launch_bounds__(64, 1) void lstm_wave(
    const int* __restrict__ x, const float* __restrict__ z,
    const float* __restrict__ wh, float* __restrict__ hb0,
    const float* __restrict__ dw, const float* __restrict__ db,
    float* __restrict__ out)
{
  const int b = blockIdx.x;
  const int l = threadIdx.x;        // 0..63, one wave
  __shared__ __align__(16) float h_lds[Hn];
  __shared__ float sm0[32], sm1[32];

  // len = sum(mask) via per-lane partial + wave butterfly (mask is 1s-then-0s)
  int msum = 0;
  #pragma unroll
  for (int i = 0; i < 8; ++i) msum += x[b*3*Tn + 2*Tn + i*64 + l];
  #pragma unroll
  for (int off = 1; off < 64; off <<= 1) msum += __shfl_xor(msum, off, 64);
  const int len = msum;             // in [128, 512]

  // weights: lane l's 4 gate columns, packed by k-pairs for v_pk_fma_f32
  f32x2 wi[32], wf[32], wg[32], wo[32];
  #pragma unroll
  for (int k2 = 0; k2 < 32; ++k2) {
    const float* r0 = wh + (size_t)(2*k2)*Gn;
    const float* r1 = wh + (size_t)(2*k2+1)*Gn;
    wi[k2] = f32x2{r0[l],       r1[l]};
    wf[k2] = f32x2{r0[64+l],    r1[64+l]};
    wg[k2] = f32x2{r0[128+l],   r1[128+l]};
    wo[k2] = f32x2{r0[192+l],   r1[192+l]};
  }

  h_lds[l] = 0.f;
  float c = 0.f, h = 0.f;
  const float* zr   = z   + (size_t)b*Tn*Gn;
  float*       hout = hb0 + (size_t)b*Tn*Hn;

  if (IS_B0) {
    // rows [len, T-1] of hout must be 0 (b1 reads them)
    for (int r = len + (l >> 4); r < Tn; r += 4)
      *reinterpret_cast<float4*>(&hout[(size_t)r*Hn + (l & 15)*4]) =
          make_float4(0.f, 0.f, 0.f, 0.f);
  }

  // depth-2 prefetch (4 loads/step: 1 address + imm offsets), drained once
  float za0, za1, za2, za3, zb0, zb1, zb2, zb3;
  {
    const float* p = zr + (size_t)(IS_B0 ? len-1 : Tn-len)*Gn + l;
    asm volatile("global_load_dword %0, %1, off"            : "=v"(za0) : "v"(p));
    asm volatile("global_load_dword %0, %1, off offset:256" : "=v"(za1) : "v"(p));
    asm volatile("global_load_dword %0, %1, off offset:512" : "=v"(za2) : "v"(p));
    asm volatile("global_load_dword %0, %1, off offset:768" : "=v"(za3) : "v"(p));
  }
  {
    const float* p = zr + (size_t)(IS_B0 ? len-2 : Tn-len+1)*Gn + l;
    asm volatile("global_load_dword %0, %1, off"            : "=v"(zb0) : "v"(p));
    asm volatile("global_load_dword %0, %1, off offset:256" : "=v"(zb1) : "v"(p));
    asm volatile("global_load_dword %0, %1, off offset:512" : "=v"(zb2) : "v"(p));
    asm volatile("global_load_dword %0, %1, off offset:768" : "=v"(zb3) : "v"(p));
  }
  asm volatile("s_waitcnt vmcnt(0)" ::: "memory");
  __builtin_amdgcn_sched_barrier(0);

#define STEP(s_, Z0, Z1, Z2, Z3)                                             \
  {                                                                          \
    if (IS_B0) asm volatile("s_waitcnt vmcnt(5)" ::: "memory");              \
    else       asm volatile("s_waitcnt vmcnt(4)" ::: "memory");              \
    __builtin_amdgcn_sched_barrier(0);                                       \
    f32x2 ai = {0.f,0.f}, af2 = {0.f,0.f}, ag2 = {0.f,0.f}, ao2 = {0.f,0.f}; \
    _Pragma("unroll")                                                        \
    for (int k4 = 0; k4 < 16; ++k4) {                                        \
      float4 hv = *reinterpret_cast<const float4*>(&h_lds[k4*4]);            \
      f32x2 h01 = {hv.x, hv.y}, h23 = {hv.z, hv.w};                          \
      PK_FMA(ai,  h01, wi[2*k4]);  PK_FMA(ai,  h23, wi[2*k4+1]);             \
      PK_FMA(af2, h01, wf[2*k4]);  PK_FMA(af2, h23, wf[2*k4+1]);             \
      PK_FMA(ag2, h01, wg[2*k4]);  PK_FMA(ag2, h23, wg[2*k4+1]);             \
      PK_FMA(ao2, h01, wo[2*k4]);  PK_FMA(ao2, h23, wo[2*k4+1]);             \
    }                                                                        \
    float a_i = (ai[0]+ai[1])   + (Z0);                                      \
    float a_f = (af2[0]+af2[1]) + (Z1);                                      \
    float a_g = (ag2[0]+ag2[1]) + (Z2);                                      \
    float a_o = (ao2[0]+ao2[1]) + (Z3);                                      \
    float ig = sigf(a_i), fg = sigf(a_f);                                    \
    float gg = tanhfast(a_g), og = sigf(a_o);                                \
    float cn_ = fmaf(fg, c, ig*gg);                                          \
    float hn_ = og * tanhfast(cn_);                                          \
    bool act_ = (s_) < len;                                                  \
    c = act_ ? cn_ : c;                                                      \
    h = act_ ? hn_ : h;                                                      \
    h_lds[l] = h;                                                            \
    if (IS_B0) {                                                             \
      int ts_ = len-1-(s_); ts_ = ts_ < 0 ? 0 : ts_;                         \
      float* sp_ = hout + (size_t)ts_*Hn + l;                                \
      asm volatile("global_store_dword %0, %1, off" :: "v"(sp_), "v"(h));    \
    }                                                                        \
    {                                                                        \
      int tn_ = IS_B0 ? (len-3-(s_)) : (Tn-len+(s_)+2);                      \
      tn_ = tn_ < 0 ? 0 : (tn_ > Tn-1 ? Tn-1 : tn_);                         \
      const float* p_ = zr + (size_t)tn_*Gn + l;                             \
      asm volatile("global_load_dword %0, %1, off"            : "=v"(Z0) : "v"(p_)); \
      asm volatile("global_load_dword %0, %1, off offset:256" : "=v"(Z1) : "v"(p_)); \
      asm volatile("global_load_dword %0, %1, off offset:512" : "=v"(Z2) : "v"(p_)); \
      asm volatile("global_load_dword %0, %1, off offset:768" : "=v"(Z3) : "v"(p_)); \
    }                                                                        \
  }

  const int lenr = (len + 1) & ~1;
  for (int s = 0; s < lenr; s += 2) {
    STEP(s+0, za0, za1, za2, za3);
    STEP(s+1, zb0, zb1, zb2, zb3);
  }
#undef STEP

  // drain all asm VMEM; keep async-written regs alive past the drain (R5 lesson)
  asm volatile("s_waitcnt vmcnt(0)" ::: "memory");
  asm volatile("" :: "v"(za0), "v"(za1), "v"(za2), "v"(za3),
                     "v"(zb0), "v"(zb1), "v"(zb2), "v"(zb3));
  __builtin_amdgcn_sched_barrier(0);

  if (!IS_B0) {
    // head: logits (C=20) + softmax; single wave, in-order DS pipe
    if (l < Cn) {
      float lg = db[l];
      #pragma unroll
      for (int k = 0; k < Hn; ++k) lg = fmaf(h_lds[k], dw[k*Cn + l], lg);
      sm0[l] = lg;
    }
    if (l < Cn) {
      float m = sm0[0];
      #pragma unroll
      for (int k = 1; k < Cn; ++k) m = fmaxf(m, sm0[k]);
      float e = __expf(sm0[l] - m);
      sm1[l] = e;
      float ssum = 0.f;
      #pragma unroll
      for (int k = 0; k < Cn; ++k) ssum += sm1[k];
      out[b*Cn + l] = e / ssum;
    }
  }
}

// ---------------------------------------------------------------------------
extern "C" void kernel_launch(void* const* d_in, const int* in_sizes, int n_in,
                              void* d_out, int out_size, void* d_ws, size_t ws_size,
                              hipStream_t stream)
{
  const int*   x        = (const int*)  d_in[0];
  const float* word_emb = (const float*)d_in[1];
  const float* pos_emb  = (const float*)d_in[2];
  // forward-branch weights d_in[3..8] are dead code in the reference
  const float* wx_b0    = (const float*)d_in[9];
  const float* wh_b0    = (const float*)d_in[10];
  const float* b_b0     = (const float*)d_in[11];
  const float* wx_b1    = (const float*)d_in[12];
  const float* wh_b1    = (const float*)d_in[13];
  const float* b_b1     = (const float*)d_in[14];
  const float* dw       = (const float*)d_in[15];
  const float* db       = (const float*)d_in[16];
  float* out = (float*)d_out;

  float* z0  = (float*)d_ws;                    // B*T*256 f32 = 33.5 MB (reused as ZX1)
  float* hb0 = z0 + (size_t)Bn*Tn*Gn;           // B*T*64  f32 =  8.4 MB

  emb_proj_kernel<<<dim3((Bn*Tn)/64), dim3(256), 0, stream>>>(
      x, word_emb, pos_emb, wx_b0, b_b0, z0);
  lstm_wave<true><<<dim3(Bn), dim3(64), 0, stream>>>(
      x, z0, wh_b0, hb0, nullptr, nullptr, nullptr);
  zx1_gemm_kernel<<<dim3((Bn*Tn)/64), dim3(256), 0, stream>>>(
      hb0, wx_b1, b_b1, z0);                    // z0 buffer reused as ZX1
  lstm_wave<false><<<dim3(Bn), dim3(64), 0, stream>>>(
      x, z0, wh_b1, hb0, dw, db, out);
}

// Round 8
// 568.645 us; speedup vs baseline: 2.2429x; 2.2429x over previous
//
#include <hip/hip_runtime.h>
#include <hip/hip_bf16.h>

#define Bn 64
#define Tn 512
#define En 128
#define Hn 64
#define Gn 256   // 4*H
#define Cn 20

typedef float f32x2 __attribute__((ext_vector_type(2)));

__device__ __forceinline__ float sigf(float x)      { return 1.f/(1.f+__expf(-x)); }
__device__ __forceinline__ float tanhfast(float x)  { return 2.f/(1.f+__expf(-2.f*x)) - 1.f; }

// ---------------------------------------------------------------------------
// Kernel A: Z0[b*T+t][j] = (word_emb[ids[b,t]] + pos_emb[t]) @ Wx_b0 + b_b0
// ---------------------------------------------------------------------------
__global__ __launch_bounds__(256, 1) void emb_proj_kernel(
    const int* __restrict__ x, const float* __restrict__ word_emb,
    const float* __restrict__ pos_emb, const float* __restrict__ wx,
    const float* __restrict__ bias, float* __restrict__ z0)
{
  __shared__ float emb[64][En];     // 32 KB
  __shared__ float wxl[32][Gn];     // 32 KB
  const int tid  = threadIdx.x;
  const int row0 = blockIdx.x * 64;

  #pragma unroll
  for (int it = 0; it < 8; ++it) {
    int idx = it*256 + tid;
    int rr  = idx >> 5;
    int e4  = (idx & 31) << 2;
    int r   = row0 + rr;
    int b   = r >> 9;
    int t   = r & (Tn-1);
    int id  = x[b*3*Tn + t];
    float4 we = *reinterpret_cast<const float4*>(&word_emb[(size_t)id*En + e4]);
    float4 pe = *reinterpret_cast<const float4*>(&pos_emb[(size_t)t*En + e4]);
    *reinterpret_cast<float4*>(&emb[rr][e4]) =
        make_float4(we.x+pe.x, we.y+pe.y, we.z+pe.z, we.w+pe.w);
  }

  const int jc = tid & 63;
  const int rg = tid >> 6;
  float acc[16][4];
  float4 bb = *reinterpret_cast<const float4*>(&bias[jc*4]);
  #pragma unroll
  for (int r = 0; r < 16; ++r) { acc[r][0]=bb.x; acc[r][1]=bb.y; acc[r][2]=bb.z; acc[r][3]=bb.w; }

  for (int ec = 0; ec < 4; ++ec) {
    __syncthreads();
    #pragma unroll
    for (int it = 0; it < 8; ++it) {
      int idx = it*256 + tid;
      int ee  = idx >> 6;
      int j4  = (idx & 63) << 2;
      *reinterpret_cast<float4*>(&wxl[ee][j4]) =
          *reinterpret_cast<const float4*>(&wx[(size_t)(ec*32+ee)*Gn + j4]);
    }
    __syncthreads();
    for (int ee = 0; ee < 32; ++ee) {
      float4 w = *reinterpret_cast<const float4*>(&wxl[ee][jc*4]);
      #pragma unroll
      for (int r = 0; r < 16; ++r) {
        float xv = emb[rg*16+r][ec*32+ee];
        acc[r][0] = fmaf(xv, w.x, acc[r][0]);
        acc[r][1] = fmaf(xv, w.y, acc[r][1]);
        acc[r][2] = fmaf(xv, w.z, acc[r][2]);
        acc[r][3] = fmaf(xv, w.w, acc[r][3]);
      }
    }
  }
  #pragma unroll
  for (int r = 0; r < 16; ++r) {
    size_t row = (size_t)row0 + rg*16 + r;
    *reinterpret_cast<float4*>(&z0[row*Gn + jc*4]) =
        make_float4(acc[r][0], acc[r][1], acc[r][2], acc[r][3]);
  }
}

// ---------------------------------------------------------------------------
// Kernel A2: ZX1[b*T+t][j] = hb0[b,t,:] @ Wx_b1 + b_b1
// ---------------------------------------------------------------------------
__global__ __launch_bounds__(256, 1) void zx1_gemm_kernel(
    const float* __restrict__ hb0, const float* __restrict__ wx,
    const float* __restrict__ bias, float* __restrict__ zx1)
{
  __shared__ float xl[64][Hn];
  __shared__ float wl[32][Gn];
  const int tid  = threadIdx.x;
  const int row0 = blockIdx.x * 64;

  #pragma unroll
  for (int it = 0; it < 4; ++it) {
    int idx = it*256 + tid;
    int rr  = idx >> 4;
    int e4  = (idx & 15) << 2;
    *reinterpret_cast<float4*>(&xl[rr][e4]) =
        *reinterpret_cast<const float4*>(&hb0[((size_t)row0+rr)*Hn + e4]);
  }

  const int jc = tid & 63;
  const int rg = tid >> 6;
  float acc[16][4];
  float4 bb = *reinterpret_cast<const float4*>(&bias[jc*4]);
  #pragma unroll
  for (int r = 0; r < 16; ++r) { acc[r][0]=bb.x; acc[r][1]=bb.y; acc[r][2]=bb.z; acc[r][3]=bb.w; }

  for (int kc = 0; kc < 2; ++kc) {
    __syncthreads();
    #pragma unroll
    for (int it = 0; it < 8; ++it) {
      int idx = it*256 + tid;
      int kk  = idx >> 6;
      int j4  = (idx & 63) << 2;
      *reinterpret_cast<float4*>(&wl[kk][j4]) =
          *reinterpret_cast<const float4*>(&wx[(size_t)(kc*32+kk)*Gn + j4]);
    }
    __syncthreads();
    for (int kk = 0; kk < 32; ++kk) {
      float4 w = *reinterpret_cast<const float4*>(&wl[kk][jc*4]);
      #pragma unroll
      for (int r = 0; r < 16; ++r) {
        float xv = xl[rg*16+r][kc*32+kk];
        acc[r][0] = fmaf(xv, w.x, acc[r][0]);
        acc[r][1] = fmaf(xv, w.y, acc[r][1]);
        acc[r][2] = fmaf(xv, w.z, acc[r][2]);
        acc[r][3] = fmaf(xv, w.w, acc[r][3]);
      }
    }
  }
  #pragma unroll
  for (int r = 0; r < 16; ++r) {
    size_t row = (size_t)row0 + rg*16 + r;
    *reinterpret_cast<float4*>(&zx1[row*Gn + jc*4]) =
        make_float4(acc[r][0], acc[r][1], acc[r][2], acc[r][3]);
  }
}

// ---------------------------------------------------------------------------
// Recurrence: 256 threads / 4 waves per batch element. Thread tid owns gate
// column tid. The 64 weight floats live in 32 f32x2 VGPR pairs consumed by
// inline-asm v_pk_fma_f32 -- the asm forces register residency (R6's
// VGPR_Count=52 proved the compiler was re-loading weights from memory
// every step; that was the hidden ~600 cy/step). One raw s_barrier per step
// (lgkm-only drain). In-loop VMEM is inline asm with counted vmcnt.
// ---------------------------------------------------------------------------
#define WAVE_BARRIER()                                        \
  do {                                                        \
    asm volatile("s_waitcnt lgkmcnt(0)" ::: "memory");        \
    __builtin_amdgcn_sched_barrier(0);                        \
    __builtin_amdgcn_s_barrier();                             \
    __builtin_amdgcn_sched_barrier(0);                        \
  } while (0)

#define PK_FMA(acc, hp, wp) \
  asm("v_pk_fma_f32 %0, %1, %2, %0" : "+v"(acc) : "v"(hp), "v"(wp))

#define PLOAD(dst, t_)                                                      \
  { const float* pp_ = zr + (size_t)(t_)*Gn + tid;                          \
    asm volatile("global_load_dword %0, %1, off" : "=v"(dst) : "v"(pp_)); }

template<bool IS_B0>
__global__ __launch_bounds__(256, 1) void lstm_fast(
    const int* __restrict__ x, const float* __restrict__ z,
    const float* __restrict__ wh, float* __restrict__ hb0,
    const float* __restrict__ dw, const float* __restrict__ db,
    float* __restrict__ out)
{
  const int b   = blockIdx.x;
  const int tid = threadIdx.x;
  const int wv  = tid >> 6;
  const int l   = tid & 63;

  __shared__ __align__(16) float z_s[2][Gn];
  __shared__ __align__(16) float h_own[4][Hn];   // per-wave private h copy
  __shared__ float sm[2][32];
  __shared__ int slen;

  if (tid == 0) slen = 0;
  __syncthreads();
  {
    int m0 = x[b*3*Tn + 2*Tn + tid];
    int m1 = x[b*3*Tn + 2*Tn + 256 + tid];
    atomicAdd(&slen, m0 + m1);
  }
  // weights: 32 f32x2 pairs (k even/odd), register-resident via asm pk_fma
  f32x2 wp[32];
  #pragma unroll
  for (int k2 = 0; k2 < 32; ++k2)
    wp[k2] = f32x2{wh[(size_t)(2*k2)*Gn + tid], wh[(size_t)(2*k2+1)*Gn + tid]};
  h_own[wv][l] = 0.f;
  __syncthreads();
  const int len = slen;             // in [T/4, T]; mask is 1s then 0s

  const float* zr   = z   + (size_t)b*Tn*Gn;
  float*       hout = hb0 + (size_t)b*Tn*Hn;
  float c = 0.f, h = 0.f;

  if (IS_B0) {
    // rows [len, T-1] of hout must be 0 (b1 consumes them)
    for (int r = len + (tid >> 4); r < Tn; r += 16)
      *reinterpret_cast<float4*>(&hout[(size_t)r*Hn + (tid & 15)*4]) =
          make_float4(0.f, 0.f, 0.f, 0.f);
  }

  // depth-4 prefetch into fixed named regs, drained ONCE before the loop.
  float zp0, zp1, zp2, zp3;
  PLOAD(zp0, IS_B0 ? len-1 : Tn-len);
  PLOAD(zp1, IS_B0 ? len-2 : Tn-len+1);
  PLOAD(zp2, IS_B0 ? len-3 : Tn-len+2);
  PLOAD(zp3, IS_B0 ? len-4 : Tn-len+3);
  asm volatile("s_waitcnt vmcnt(0)" ::: "memory");
  __builtin_amdgcn_sched_barrier(0);

#define STEP(s_, ZREG)                                                       \
  {                                                                          \
    if (IS_B0) asm volatile("s_waitcnt vmcnt(7)" ::: "memory");              \
    else       asm volatile("s_waitcnt vmcnt(3)" ::: "memory");              \
    __builtin_amdgcn_sched_barrier(0);                                       \
    f32x2 acc2 = {ZREG, 0.f};                                                \
    _Pragma("unroll")                                                        \
    for (int k4 = 0; k4 < 16; ++k4) {                                        \
      float4 hv = *reinterpret_cast<const float4*>(&h_own[wv][k4*4]);        \
      f32x2 h01 = {hv.x, hv.y}, h23 = {hv.z, hv.w};                          \
      PK_FMA(acc2, h01, wp[2*k4]);                                           \
      PK_FMA(acc2, h23, wp[2*k4+1]);                                         \
    }                                                                        \
    z_s[(s_)&1][tid] = acc2[0] + acc2[1];                                    \
    { /* issue load for step s_+4 early (max slack) */                       \
      int tn_ = IS_B0 ? (len-5-(s_)) : (Tn-len+(s_)+4);                      \
      tn_ = tn_ < 0 ? 0 : (tn_ > Tn-1 ? Tn-1 : tn_);                         \
      const float* pp_ = zr + (size_t)tn_*Gn + tid;                          \
      asm volatile("global_load_dword %0, %1, off" : "=v"(ZREG) : "v"(pp_)); \
    }                                                                        \
    WAVE_BARRIER();                                                          \
    float g0 = z_s[(s_)&1][l],      g1 = z_s[(s_)&1][Hn+l];                  \
    float g2 = z_s[(s_)&1][2*Hn+l], g3 = z_s[(s_)&1][3*Hn+l];                \
    float ig = sigf(g0), fg = sigf(g1);                                      \
    float gg = tanhfast(g2), og = sigf(g3);                                  \
    float cn_ = fmaf(fg, c, ig*gg);                                          \
    float hn_ = og * tanhfast(cn_);                                          \
    bool act_ = (s_) < len;                                                  \
    c = act_ ? cn_ : c;                                                      \
    h = act_ ? hn_ : h;                                                      \
    h_own[wv][l] = h;                                                        \
    if (IS_B0) {                                                             \
      int ts_ = len-1-(s_); ts_ = ts_ < 0 ? 0 : ts_;                         \
      float* sp_ = hout + (size_t)ts_*Hn + l;                                \
      asm volatile("global_store_dword %0, %1, off" :: "v"(sp_), "v"(h));    \
    }                                                                        \
  }

  const int lenr = (len + 3) & ~3;
  for (int s = 0; s < lenr; s += 4) {
    STEP(s+0, zp0);
    STEP(s+1, zp1);
    STEP(s+2, zp2);
    STEP(s+3, zp3);
  }
#undef STEP

  // drain asm VMEM; keep async-written regs alive past the drain (R5 lesson)
  asm volatile("s_waitcnt vmcnt(0)" ::: "memory");
  asm volatile("" :: "v"(zp0), "v"(zp1), "v"(zp2), "v"(zp3));
  __builtin_amdgcn_sched_barrier(0);

  if (!IS_B0) {
    // head: logits (C=20) + softmax; wave-0 lanes, wave-synchronous LDS
    if (tid < Cn) {
      float lg = db[tid];
      #pragma unroll
      for (int k = 0; k < Hn; ++k) lg = fmaf(h_own[0][k], dw[k*Cn + tid], lg);
      sm[0][tid] = lg;
    }
    if (tid < Cn) {
      float m = sm[0][0];
      #pragma unroll
      for (int k = 1; k < Cn; ++k) m = fmaxf(m, sm[0][k]);
      float e = __expf(sm[0][tid] - m);
      sm[1][tid] = e;
      float ssum = 0.f;
      #pragma unroll
      for (int k = 0; k < Cn; ++k) ssum += sm[1][k];
      out[b*Cn + tid] = e / ssum;
    }
  }
}

// ---------------------------------------------------------------------------
extern "C" void kernel_launch(void* const* d_in, const int* in_sizes, int n_in,
                              void* d_out, int out_size, void* d_ws, size_t ws_size,
                              hipStream_t stream)
{
  const int*   x        = (const int*)  d_in[0];
  const float* word_emb = (const float*)d_in[1];
  const float* pos_emb  = (const float*)d_in[2];
  // forward-branch weights d_in[3..8] are dead code in the reference
  const float* wx_b0    = (const float*)d_in[9];
  const float* wh_b0    = (const float*)d_in[10];
  const float* b_b0     = (const float*)d_in[11];
  const float* wx_b1    = (const float*)d_in[12];
  const float* wh_b1    = (const float*)d_in[13];
  const float* b_b1     = (const float*)d_in[14];
  const float* dw       = (const float*)d_in[15];
  const float* db       = (const float*)d_in[16];
  float* out = (float*)d_out;

  float* z0  = (float*)d_ws;                    // B*T*256 f32 = 33.5 MB (reused as ZX1)
  float* hb0 = z0 + (size_t)Bn*Tn*Gn;           // B*T*64  f32 =  8.4 MB

  emb_proj_kernel<<<dim3((Bn*Tn)/64), dim3(256), 0, stream>>>(
      x, word_emb, pos_emb, wx_b0, b_b0, z0);
  lstm_fast<true><<<dim3(Bn), dim3(256), 0, stream>>>(
      x, z0, wh_b0, hb0, nullptr, nullptr, nullptr);
  zx1_gemm_kernel<<<dim3((Bn*Tn)/64), dim3(256), 0, stream>>>(
      hb0, wx_b1, b_b1, z0);                    // z0 buffer reused as ZX1
  lstm_fast<false><<<dim3(Bn), dim3(256), 0, stream>>>(
      x, z0, wh_b1, hb0, dw, db, out);
}